// Round 8
// baseline (134.365 us; speedup 1.0000x reference)
//
#include <hip/hip_runtime.h>

#define W 144
#define PLANE (W * W)
#define VOL (W * W * W)
#define NB 2
#define WIN 11
#define PAD 5
#define YCH 3               // y-chunks (serial prefix per chunk)
#define YCL (W / YCH)       // 48
#define PR (YCL + WIN)      // 59 stored prefix rows per chunk
#define ZCHUNKS 3
#define ZCHUNK (W / ZCHUNKS)
#define NCELL 256

// DPP lane shift with old=0 (edge lanes read 0). wave_shr:1 = 0x138, wave_shl:1 = 0x130.
template <int CTRL>
__device__ __forceinline__ float dpp0(float x) {
    return __int_as_float(
        __builtin_amdgcn_update_dpp(0, __float_as_int(x), CTRL, 0xf, 0xf, false));
}
#define SHR1(v) dpp0<0x138>(v)
#define SHL1(v) dpp0<0x130>(v)

// Lane l holds v at x = 4l-8 .. 4l-5. Returns the 11-tap x-window sums for its
// 4 positions using only +-1/+-2 lane shifts (no bpermute, depth ~3).
__device__ __forceinline__ float4 win11x4(const float4 v) {
    const float pre2 = v.x + v.y;
    const float pre3 = pre2 + v.z;
    const float q = pre3 + v.w;
    const float suf2 = v.z + v.w;
    const float suf3 = suf2 + v.y;
    const float qm1 = SHR1(q);
    const float sfx2m1 = SHR1(suf2);
    const float sfx3m1 = SHR1(suf3);
    const float sfx1m2 = SHR1(SHR1(v.w));
    const float qp1 = SHL1(q);
    const float pfx2p1 = SHL1(pre2);
    const float pfx3p1 = SHL1(pre3);
    const float pfx1p2 = SHL1(SHL1(v.x));
    float4 w;
    w.x = (sfx1m2 + qm1) + (q + pfx2p1);   // [4l-13, 4l-3]
    w.y = qm1 + (q + pfx3p1);
    w.z = sfx3m1 + (q + qp1);
    w.w = (sfx2m1 + q) + (qp1 + pfx1p2);
    return w;
}

// kA: per (b,z,y-chunk) wave covering the FULL x-row (fat-4 lanes).
// Serial y over 59 rows (48 core + 11 halo): compute 4 raw fields, 11-tap
// x-window via win11x4, accumulate chunk-local y-prefix P, store P rows
// (voxel-float4 = 4 fields). Also accumulates L1 on core rows.
__global__ __launch_bounds__(64) void
kA_xyprefix(const float* __restrict__ pred, const float* __restrict__ targ,
            float4* __restrict__ ws2, double* __restrict__ accL1) {
    const int l = threadIdx.x;
    int wg = blockIdx.x;
    const int c = wg % YCH; wg /= YCH;
    const int z = wg % W; wg /= W;
    const int b = wg;

    const int xbase = 4 * l - 8;                 // lanes 2..37 active
    const bool vx = (xbase >= 0) && (xbase < W);
    const float* __restrict__ pb = pred + (size_t)b * VOL + (size_t)z * PLANE + xbase;
    const float* __restrict__ tb = targ + (size_t)b * VOL + (size_t)z * PLANE + xbase;
    float4* __restrict__ orow = ws2 + ((size_t)((b * W + z) * YCH + c)) * PR * W;

    const int g0 = c * YCL - (PAD + 1);          // first stored row (y-6 of first core y)
    const int NS = PR;                           // 59 steps

    float4 P0 = make_float4(0.f, 0.f, 0.f, 0.f);
    float4 P1 = P0, P2 = P0, P3 = P0;
    float l1 = 0.f;
    const float4 z4 = make_float4(0.f, 0.f, 0.f, 0.f);

    // depth-4 prefetch, named slots
    float4 pp0 = z4, pp1 = z4, pp2 = z4, pp3 = z4;
    float4 tt0 = z4, tt1 = z4, tt2 = z4, tt3 = z4;
#define LOADROW(PP, TT, I)                                                    \
    {                                                                         \
        const int g_ = g0 + (I);                                              \
        if (vx && (I) < NS && g_ >= 0 && g_ < W) {                            \
            PP = *reinterpret_cast<const float4*>(pb + (size_t)g_ * W);       \
            TT = *reinterpret_cast<const float4*>(tb + (size_t)g_ * W);       \
        } else { PP = z4; TT = z4; }                                          \
    }
    LOADROW(pp0, tt0, 0)
    LOADROW(pp1, tt1, 1)
    LOADROW(pp2, tt2, 2)
    LOADROW(pp3, tt3, 3)

#define STEP(I, PP, TT)                                                       \
    if ((I) < NS) {                                                           \
        const float4 p4 = PP, t4 = TT;                                        \
        LOADROW(PP, TT, (I) + 4)                                              \
        if (vx && (I) >= PAD + 1 && (I) < PAD + 1 + YCL) {                    \
            l1 += fabsf(p4.x - t4.x) + fabsf(p4.y - t4.y) +                   \
                  fabsf(p4.z - t4.z) + fabsf(p4.w - t4.w);                    \
        }                                                                     \
        const float4 vpt = make_float4(p4.x * t4.x, p4.y * t4.y,              \
                                       p4.z * t4.z, p4.w * t4.w);             \
        const float4 vsq = make_float4(fmaf(p4.x, p4.x, t4.x * t4.x),         \
                                       fmaf(p4.y, p4.y, t4.y * t4.y),         \
                                       fmaf(p4.z, p4.z, t4.z * t4.z),         \
                                       fmaf(p4.w, p4.w, t4.w * t4.w));        \
        const float4 w0 = win11x4(p4);                                        \
        const float4 w1 = win11x4(t4);                                        \
        const float4 w2 = win11x4(vpt);                                       \
        const float4 w3 = win11x4(vsq);                                       \
        P0.x += w0.x; P0.y += w0.y; P0.z += w0.z; P0.w += w0.w;               \
        P1.x += w1.x; P1.y += w1.y; P1.z += w1.z; P1.w += w1.w;               \
        P2.x += w2.x; P2.y += w2.y; P2.z += w2.z; P2.w += w2.w;               \
        P3.x += w3.x; P3.y += w3.y; P3.z += w3.z; P3.w += w3.w;               \
        if (vx) {                                                             \
            float4* r_ = orow + (size_t)(I) * W + xbase;                      \
            r_[0] = make_float4(P0.x, P1.x, P2.x, P3.x);                      \
            r_[1] = make_float4(P0.y, P1.y, P2.y, P3.y);                      \
            r_[2] = make_float4(P0.z, P1.z, P2.z, P3.z);                      \
            r_[3] = make_float4(P0.w, P1.w, P2.w, P3.w);                      \
        }                                                                     \
    }

    for (int ii = 0; ii < 60; ii += 4) {
        STEP(ii + 0, pp0, tt0)
        STEP(ii + 1, pp1, tt1)
        STEP(ii + 2, pp2, tt2)
        STEP(ii + 3, pp3, tt3)
    }
#undef STEP
#undef LOADROW

    // wave-level reduction of l1, one atomic per wave
    l1 += __shfl_xor(l1, 32);
    l1 += __shfl_xor(l1, 16);
    l1 += __shfl_xor(l1, 8);
    l1 += __shfl_xor(l1, 4);
    l1 += __shfl_xor(l1, 2);
    l1 += __shfl_xor(l1, 1);
    if (l == 0) atomicAdd(&accL1[blockIdx.x & (NCELL - 1)], (double)l1);
}

// K3: xy-window = P(y+5) - P(y-6) (two float4 reads), z-ring, SSIM, reduce.
__global__ void k3_zpass(const float4* __restrict__ ws2, double* __restrict__ accS) {
    const int x = threadIdx.x;
    int bid = blockIdx.x;
    const int zc = bid % ZCHUNKS; bid /= ZCHUNKS;
    const int y = bid % W; bid /= W;
    const int b = bid;
    const int zstart = zc * ZCHUNK;

    const int c = y / YCL;
    const int r_hi = y + WIN - c * YCL;   // row of P(y+5)
    const int r_lo = y - c * YCL;         // row of P(y-6)  (==0 rows hold P=0)

    const size_t zstride = (size_t)YCH * PR * W;
    const size_t base_hi = (size_t)b * W * zstride + (size_t)c * PR * W + (size_t)r_hi * W + x;
    const size_t base_lo = (size_t)b * W * zstride + (size_t)c * PR * W + (size_t)r_lo * W + x;

    float r0[WIN], r1[WIN], r2[WIN], r3[WIN];
    float s0 = 0.f, s1 = 0.f, s2 = 0.f, s3 = 0.f;
#pragma unroll
    for (int k = 0; k < WIN; ++k) { r0[k] = 0.f; r1[k] = 0.f; r2[k] = 0.f; r3[k] = 0.f; }

    const float inv = 1.0f / 1331.0f;
    const float C1 = 0.01f * 0.01f;
    const float C2 = 0.03f * 0.03f;
    float ssim_acc = 0.f;

    const int NSTEP = ZCHUNK + 2 * PAD;  // 58
    for (int cc = 0; cc < 6; ++cc) {
#pragma unroll
        for (int u = 0; u < WIN; ++u) {
            const int i = cc * WIN + u;
            if (i < NSTEP) {
                const int zl = zstart - PAD + i;
                float4 w = make_float4(0.f, 0.f, 0.f, 0.f);
                if (zl >= 0 && zl < W) {
                    const float4 hi = ws2[base_hi + (size_t)zl * zstride];
                    const float4 lo = ws2[base_lo + (size_t)zl * zstride];
                    w = make_float4(hi.x - lo.x, hi.y - lo.y, hi.z - lo.z, hi.w - lo.w);
                }
                s0 += w.x - r0[u]; r0[u] = w.x;
                s1 += w.y - r1[u]; r1[u] = w.y;
                s2 += w.z - r2[u]; r2[u] = w.z;
                s3 += w.w - r3[u]; r3[u] = w.w;
                if (i >= 2 * PAD) {
                    const float mu_p = s0 * inv;
                    const float mu_t = s1 * inv;
                    const float ept = s2 * inv;
                    const float esq = s3 * inv;
                    const float mupt = mu_p * mu_t;
                    const float musq = mu_p * mu_p + mu_t * mu_t;
                    const float sig_pt = ept - mupt;
                    const float sigsum = esq - musq;
                    const float num = (2.f * mupt + C1) * (2.f * sig_pt + C2);
                    const float den = (musq + C1) * (sigsum + C2);
                    ssim_acc += num / den;
                }
            }
        }
    }

    __shared__ float red[W];
    red[x] = ssim_acc;
    __syncthreads();
    if (x < 16) {
        float s2r = 0.f;
#pragma unroll
        for (int k = 0; k < 9; ++k) s2r += red[x + 16 * k];
        s2r += __shfl_down(s2r, 8);
        s2r += __shfl_down(s2r, 4);
        s2r += __shfl_down(s2r, 2);
        s2r += __shfl_down(s2r, 1);
        if (x == 0) atomicAdd(&accS[blockIdx.x & (NCELL - 1)], (double)s2r);
    }
}

// K4: reduce the 2x256 cells, write the 3 outputs.
__global__ void k4_final(const double* __restrict__ accL1, const double* __restrict__ accS,
                         float* __restrict__ out) {
    const int x = threadIdx.x;
    __shared__ double d1[NCELL];
    __shared__ double d2[NCELL];
    d1[x] = accL1[x];
    d2[x] = accS[x];
    __syncthreads();
    for (int s = NCELL / 2; s > 0; s >>= 1) {
        if (x < s) {
            d1[x] += d1[x + s];
            d2[x] += d2[x + s];
        }
        __syncthreads();
    }
    if (x == 0) {
        const double n = (double)NB * (double)VOL;
        const double l1 = d1[0] / n;
        const double ssim_loss = 1.0 - d2[0] / n;
        const double total = l1 + 0.5 * ssim_loss;
        out[0] = (float)total;
        out[1] = (float)l1;
        out[2] = (float)ssim_loss;
    }
}

extern "C" void kernel_launch(void* const* d_in, const int* in_sizes, int n_in,
                              void* d_out, int out_size, void* d_ws, size_t ws_size,
                              hipStream_t stream) {
    const float* pred = (const float*)d_in[0];
    const float* targ = (const float*)d_in[1];
    float* out = (float*)d_out;
    float4* ws2 = (float4*)d_ws;
    const size_t ws2_elems = (size_t)NB * W * YCH * PR * W;   // 7,340,544 float4 = 117.4 MB
    double* accL1 = (double*)((char*)d_ws + ws2_elems * sizeof(float4));
    double* accS = accL1 + NCELL;

    hipMemsetAsync(accL1, 0, 2 * NCELL * sizeof(double), stream);
    kA_xyprefix<<<NB * W * YCH, 64, 0, stream>>>(pred, targ, ws2, accL1);
    k3_zpass<<<NB * W * ZCHUNKS, W, 0, stream>>>(ws2, accS);
    k4_final<<<1, NCELL, 0, stream>>>(accL1, accS, out);
}

// Round 9
// 133.219 us; speedup vs baseline: 1.0086x; 1.0086x over previous
//
#include <hip/hip_runtime.h>

#define W 144
#define PLANE (W * W)
#define VOL (W * W * W)
#define NB 2
#define WIN 11
#define PAD 5
#define YCH 12
#define YC (W / YCH)        // 12
#define NSTEP (YC + 2 * PAD)  // 22 = 2*WIN
#define ZCHUNKS 3
#define ZCHUNK (W / ZCHUNKS)
#define NCELL 256
#define WPB 4

// DPP lane shift with old=0 (edge lanes read 0). wave_shr:1=0x138, wave_shl:1=0x130.
template <int CTRL>
__device__ __forceinline__ float dpp0(float x) {
    return __int_as_float(
        __builtin_amdgcn_update_dpp(0, __float_as_int(x), CTRL, 0xf, 0xf, false));
}
#define SHR1(v) dpp0<0x138>(v)
#define SHL1(v) dpp0<0x130>(v)

// Lane l holds v at x = 4l-8 .. 4l-5. 11-tap x-window sums for its 4 positions
// using only wave shifts (verified on-chip in R8, absmax 0).
__device__ __forceinline__ float4 win11x4(const float4 v) {
    const float pre2 = v.x + v.y;
    const float pre3 = pre2 + v.z;
    const float q = pre3 + v.w;
    const float suf2 = v.z + v.w;
    const float suf3 = suf2 + v.y;
    const float qm1 = SHR1(q);
    const float sfx2m1 = SHR1(suf2);
    const float sfx3m1 = SHR1(suf3);
    const float sfx1m2 = SHR1(SHR1(v.w));
    const float qp1 = SHL1(q);
    const float pfx2p1 = SHL1(pre2);
    const float pfx3p1 = SHL1(pre3);
    const float pfx1p2 = SHL1(SHL1(v.x));
    float4 w;
    w.x = (sfx1m2 + qm1) + (q + pfx2p1);
    w.y = qm1 + (q + pfx3p1);
    w.z = sfx3m1 + (q + qp1);
    w.w = (sfx2m1 + q) + (qp1 + pfx1p2);
    return w;
}

// kB: fused x+y pass. Wave = (b, z, y-chunk of 12). Fat-4 lanes cover the
// full x-row (lanes 0..39 staged, 2..37 own outputs). Per y-row: 4 fields ->
// win11x4 -> in-register y-ring (float4[4][11], static slots) -> one float4
// store per owned voxel. Rolled outer loop (2 x 11 steps) keeps I-footprint
// small; depth-1 register prefetch.
__global__ __launch_bounds__(WPB * 64) void
kB_xypass(const float* __restrict__ pred, const float* __restrict__ targ,
          float4* __restrict__ ws, double* __restrict__ accL1) {
    const int tid = threadIdx.x;
    const int l = tid & 63;
    const int wid = tid >> 6;
    int wg = blockIdx.x * WPB + wid;
    const int yc = wg % YCH; wg /= YCH;
    const int z = wg % W; wg /= W;
    const int b = wg;
    const int y0 = yc * YC;

    const int xbase = 4 * l - 8;                 // lanes 0..39 staged
    const bool vx = (xbase >= 0) && (xbase < W); // owner lanes 2..37
    const float* __restrict__ pb = pred + (size_t)b * VOL + (size_t)z * PLANE + xbase;
    const float* __restrict__ tb = targ + (size_t)b * VOL + (size_t)z * PLANE + xbase;
    float4* __restrict__ ob = ws + (size_t)b * VOL + (size_t)z * PLANE;

    const float4 z4 = make_float4(0.f, 0.f, 0.f, 0.f);
    float4 r0[WIN], r1[WIN], r2[WIN], r3[WIN];
#pragma unroll
    for (int k = 0; k < WIN; ++k) { r0[k] = z4; r1[k] = z4; r2[k] = z4; r3[k] = z4; }
    float4 s0 = z4, s1 = z4, s2 = z4, s3 = z4;
    float l1 = 0.f;

    // depth-1 prefetch of row i=0 (yl = y0-5; <0 only possible at yc==0)
    float4 pa = z4, ta = z4;
    if (vx && (y0 - PAD) >= 0) {
        pa = *reinterpret_cast<const float4*>(pb + (size_t)(y0 - PAD) * W);
        ta = *reinterpret_cast<const float4*>(tb + (size_t)(y0 - PAD) * W);
    }

#pragma unroll 1
    for (int c = 0; c < 2; ++c) {
#pragma unroll
        for (int u = 0; u < WIN; ++u) {
            const int i = c * WIN + u;
            const int yl = y0 - PAD + i;
            const float4 p4 = pa, t4 = ta;
            // prefetch row i+1
            pa = z4; ta = z4;
            {
                const int g = yl + 1;
                if (vx && i < NSTEP - 1 && g >= 0 && g < W) {
                    pa = *reinterpret_cast<const float4*>(pb + (size_t)g * W);
                    ta = *reinterpret_cast<const float4*>(tb + (size_t)g * W);
                }
            }

            // L1 on core rows (pad lanes hold zeros -> contribute 0)
            if (i >= PAD && i < PAD + YC) {
                l1 += (fabsf(p4.x - t4.x) + fabsf(p4.y - t4.y)) +
                      (fabsf(p4.z - t4.z) + fabsf(p4.w - t4.w));
            }

            const float4 vpt = make_float4(p4.x * t4.x, p4.y * t4.y,
                                           p4.z * t4.z, p4.w * t4.w);
            const float4 vsq = make_float4(fmaf(p4.x, p4.x, t4.x * t4.x),
                                           fmaf(p4.y, p4.y, t4.y * t4.y),
                                           fmaf(p4.z, p4.z, t4.z * t4.z),
                                           fmaf(p4.w, p4.w, t4.w * t4.w));
            const float4 w0 = win11x4(p4);
            const float4 w1 = win11x4(t4);
            const float4 w2 = win11x4(vpt);
            const float4 w3 = win11x4(vsq);

            // y running window, static ring slot u
            s0.x += w0.x - r0[u].x; s0.y += w0.y - r0[u].y;
            s0.z += w0.z - r0[u].z; s0.w += w0.w - r0[u].w; r0[u] = w0;
            s1.x += w1.x - r1[u].x; s1.y += w1.y - r1[u].y;
            s1.z += w1.z - r1[u].z; s1.w += w1.w - r1[u].w; r1[u] = w1;
            s2.x += w2.x - r2[u].x; s2.y += w2.y - r2[u].y;
            s2.z += w2.z - r2[u].z; s2.w += w2.w - r2[u].w; r2[u] = w2;
            s3.x += w3.x - r3[u].x; s3.y += w3.y - r3[u].y;
            s3.z += w3.z - r3[u].z; s3.w += w3.w - r3[u].w; r3[u] = w3;

            if (i >= 2 * PAD) {
                const int y_out = y0 + i - 2 * PAD;
                if (vx) {
                    float4* r_ = ob + (size_t)y_out * W + xbase;
                    r_[0] = make_float4(s0.x, s1.x, s2.x, s3.x);
                    r_[1] = make_float4(s0.y, s1.y, s2.y, s3.y);
                    r_[2] = make_float4(s0.z, s1.z, s2.z, s3.z);
                    r_[3] = make_float4(s0.w, s1.w, s2.w, s3.w);
                }
            }
        }
    }

    // wave-level reduction of l1, one atomic per wave
    l1 += __shfl_xor(l1, 32);
    l1 += __shfl_xor(l1, 16);
    l1 += __shfl_xor(l1, 8);
    l1 += __shfl_xor(l1, 4);
    l1 += __shfl_xor(l1, 2);
    l1 += __shfl_xor(l1, 1);
    if (l == 0) atomicAdd(&accL1[(blockIdx.x * WPB + wid) & (NCELL - 1)], (double)l1);
}

// K3: z-window running sum (static ring) over the float4 field stream + SSIM.
// (Unchanged from R6 — verified.)
__global__ void k3_zpass(const float4* __restrict__ ws, double* __restrict__ accS) {
    const int x = threadIdx.x;
    int bid = blockIdx.x;
    const int c = bid % ZCHUNKS; bid /= ZCHUNKS;
    const int y = bid % W; bid /= W;
    const int b = bid;
    const int zstart = c * ZCHUNK;

    const float4* F = ws + (size_t)b * VOL + (size_t)y * W + x;

    float r0[WIN], r1[WIN], r2[WIN], r3[WIN];
    float s0 = 0.f, s1 = 0.f, s2 = 0.f, s3 = 0.f;
#pragma unroll
    for (int k = 0; k < WIN; ++k) { r0[k] = 0.f; r1[k] = 0.f; r2[k] = 0.f; r3[k] = 0.f; }

    const float inv = 1.0f / 1331.0f;
    const float C1 = 0.01f * 0.01f;
    const float C2 = 0.03f * 0.03f;
    float ssim_acc = 0.f;

    const int NZ = ZCHUNK + 2 * PAD;  // 58
    for (int cc = 0; cc < 6; ++cc) {
#pragma unroll
        for (int u = 0; u < WIN; ++u) {
            const int i = cc * WIN + u;
            if (i < NZ) {
                const int zl = zstart - PAD + i;
                float4 v = make_float4(0.f, 0.f, 0.f, 0.f);
                if (zl >= 0 && zl < W) v = F[(size_t)zl * PLANE];
                s0 += v.x - r0[u]; r0[u] = v.x;
                s1 += v.y - r1[u]; r1[u] = v.y;
                s2 += v.z - r2[u]; r2[u] = v.z;
                s3 += v.w - r3[u]; r3[u] = v.w;
                if (i >= 2 * PAD) {
                    const float mu_p = s0 * inv;
                    const float mu_t = s1 * inv;
                    const float ept = s2 * inv;
                    const float esq = s3 * inv;
                    const float mupt = mu_p * mu_t;
                    const float musq = mu_p * mu_p + mu_t * mu_t;
                    const float sig_pt = ept - mupt;
                    const float sigsum = esq - musq;
                    const float num = (2.f * mupt + C1) * (2.f * sig_pt + C2);
                    const float den = (musq + C1) * (sigsum + C2);
                    ssim_acc += num / den;
                }
            }
        }
    }

    __shared__ float red[W];
    red[x] = ssim_acc;
    __syncthreads();
    if (x < 16) {
        float s2r = 0.f;
#pragma unroll
        for (int k = 0; k < 9; ++k) s2r += red[x + 16 * k];
        s2r += __shfl_down(s2r, 8);
        s2r += __shfl_down(s2r, 4);
        s2r += __shfl_down(s2r, 2);
        s2r += __shfl_down(s2r, 1);
        if (x == 0) atomicAdd(&accS[blockIdx.x & (NCELL - 1)], (double)s2r);
    }
}

// K4: reduce the 2x256 cells, write the 3 outputs.
__global__ void k4_final(const double* __restrict__ accL1, const double* __restrict__ accS,
                         float* __restrict__ out) {
    const int x = threadIdx.x;
    __shared__ double d1[NCELL];
    __shared__ double d2[NCELL];
    d1[x] = accL1[x];
    d2[x] = accS[x];
    __syncthreads();
    for (int s = NCELL / 2; s > 0; s >>= 1) {
        if (x < s) {
            d1[x] += d1[x + s];
            d2[x] += d2[x + s];
        }
        __syncthreads();
    }
    if (x == 0) {
        const double n = (double)NB * (double)VOL;
        const double l1 = d1[0] / n;
        const double ssim_loss = 1.0 - d2[0] / n;
        const double total = l1 + 0.5 * ssim_loss;
        out[0] = (float)total;
        out[1] = (float)l1;
        out[2] = (float)ssim_loss;
    }
}

extern "C" void kernel_launch(void* const* d_in, const int* in_sizes, int n_in,
                              void* d_out, int out_size, void* d_ws, size_t ws_size,
                              hipStream_t stream) {
    const float* pred = (const float*)d_in[0];
    const float* targ = (const float*)d_in[1];
    float* out = (float*)d_out;
    float4* ws = (float4*)d_ws;
    double* accL1 = (double*)((char*)d_ws + (size_t)NB * VOL * sizeof(float4));
    double* accS = accL1 + NCELL;

    hipMemsetAsync(accL1, 0, 2 * NCELL * sizeof(double), stream);
    const int nwaves = NB * W * YCH;  // 3456
    kB_xypass<<<nwaves / WPB, WPB * 64, 0, stream>>>(pred, targ, ws, accL1);
    k3_zpass<<<NB * W * ZCHUNKS, W, 0, stream>>>(ws, accS);
    k4_final<<<1, NCELL, 0, stream>>>(accL1, accS, out);
}